// Round 1
// baseline (939.675 us; speedup 1.0000x reference)
//
#include <hip/hip_runtime.h>

// NeighConv: B=2, C=256, N=4096, K=16
// Pipeline:
//  1) sq_kernel:    sq32[p], sq64[p] = ||x_p||^2
//  2) xt_kernel:    xt[p][c] = x[b][c][i]   (point-major features)
//  3) wt_kernel:    Wt[d][c] = W[c][d]      (512x256)
//  4) dist_topk:    per (batch, 128-query tile, 1/8 j-split): fp32 v=sq_j-2*dot
//                   ranking, keep top-20 (slack) -> cand_i
//  5) merge_rerank: fp64 re-rank of 160 candidates -> true top-16 + cosine wgt
//  6) y_kernel:     Y1[p]=feat@W1^T, Y2[p]=feat@W2^T + b
//  7) final_kernel: out[b][c][i] = max_k w_k*(Y1[nk][c]+Y2[m][c])

#define B_ 2
#define C_ 256
#define N_ 4096
#define K_ 16

// ---------------- 1) squared norms ----------------
__global__ void sq_kernel(const float* __restrict__ x,
                          float* __restrict__ sq32, double* __restrict__ sq64) {
    int p = blockIdx.x * 256 + threadIdx.x;           // 0..8191
    int b = p >> 12, i = p & 4095;
    const float* xb = x + ((size_t)b << 20) + i;
    double acc = 0.0;
    #pragma unroll 8
    for (int c = 0; c < C_; ++c) {
        double v = (double)xb[(size_t)c << 12];
        acc = fma(v, v, acc);
    }
    sq64[p] = acc;
    sq32[p] = (float)acc;
}

// ---------------- 2) transpose x -> xt[p][c] ----------------
__global__ void xt_kernel(const float* __restrict__ x, float* __restrict__ xt) {
    __shared__ float tile[64][65];
    int i0 = blockIdx.x * 64;     // 64 tiles over N
    int c0 = blockIdx.y * 64;     // 4 tiles over C
    int b  = blockIdx.z;
    const float* xb = x + ((size_t)b << 20);
    int tid = threadIdx.x;
    int tx = tid & 63, tyy = tid >> 6;
    for (int r = tyy; r < 64; r += 4)
        tile[r][tx] = xb[(size_t)(c0 + r) * N_ + i0 + tx];
    __syncthreads();
    float* xtb = xt + ((size_t)b << 20);
    for (int r = tyy; r < 64; r += 4)
        xtb[(size_t)(i0 + r) * C_ + c0 + tx] = tile[tx][r];
}

// ---------------- 3) transpose W -> Wt[d][c] ----------------
__global__ void wt_kernel(const float* __restrict__ W, float* __restrict__ Wt) {
    __shared__ float tile[64][65];
    int d0 = blockIdx.x * 64;     // 8 tiles over 512
    int c0 = blockIdx.y * 64;     // 4 tiles over 256
    int tid = threadIdx.x;
    int tx = tid & 63, tyy = tid >> 6;
    for (int r = tyy; r < 64; r += 4)
        tile[r][tx] = W[(size_t)(c0 + r) * 512 + d0 + tx];
    __syncthreads();
    for (int r = tyy; r < 64; r += 4)
        Wt[(size_t)(d0 + r) * C_ + c0 + tx] = tile[tx][r];
}

// ---------------- 4) fused distance + per-split top-20 ----------------
// grid (32 qtiles, 8 splits, 2 batches), block 256.
// LDS: qf 8K + jf 8K + dt 32K + topd 10K + topi 5K = 63.0 KB
#define DKC 16
#define TOPC 20
__launch_bounds__(256, 2)
__global__ void dist_topk_kernel(const float* __restrict__ x,
                                 const float* __restrict__ sq32,
                                 int* __restrict__ cand_i) {
    __shared__ float qf[DKC][128];
    __shared__ float jf[DKC][128];
    __shared__ float dt[64][128];
    __shared__ float topd[128][TOPC];
    __shared__ unsigned short topi[128][TOPC];

    int qt = blockIdx.x;
    int s  = blockIdx.y;
    int b  = blockIdx.z;
    int q0 = qt << 7;
    int jbase = s << 9;                  // s*512
    const float* xb = x + ((size_t)b << 20);
    int tid = threadIdx.x;
    int tx = tid & 15, ty = tid >> 4;
    int tx4 = tx << 2, ty4 = ty << 2;
    int bN = b << 12;

    for (int e = tid; e < 128 * TOPC; e += 256)
        ((float*)topd)[e] = 3.0e38f;
    float worst = 3.0e38f;
    int wpos = 0;

    for (int t = 0; t < 4; ++t) {        // 4 column tiles of 128
        int j0 = jbase + (t << 7);
        float acc[8][8];
        #pragma unroll
        for (int a = 0; a < 8; ++a)
            #pragma unroll
            for (int b2 = 0; b2 < 8; ++b2) acc[a][b2] = 0.f;

        for (int cc0 = 0; cc0 < C_; cc0 += DKC) {
            __syncthreads();
            // stage DKC x 128 of q-features and j-features (scalar, conflict-free)
            for (int e = tid; e < DKC * 128; e += 256) {
                int cl = e >> 7, qq = e & 127;
                const float* src = xb + ((size_t)(cc0 + cl) << 12);
                qf[cl][qq] = src[q0 + qq];
                jf[cl][qq] = src[j0 + qq];
            }
            __syncthreads();
            #pragma unroll
            for (int c = 0; c < DKC; ++c) {
                float4 qv0 = *(const float4*)&qf[c][ty4];
                float4 qv1 = *(const float4*)&qf[c][64 + ty4];
                float4 jv0 = *(const float4*)&jf[c][tx4];
                float4 jv1 = *(const float4*)&jf[c][64 + tx4];
                float qa[8] = {qv0.x, qv0.y, qv0.z, qv0.w, qv1.x, qv1.y, qv1.z, qv1.w};
                float ja[8] = {jv0.x, jv0.y, jv0.z, jv0.w, jv1.x, jv1.y, jv1.z, jv1.w};
                #pragma unroll
                for (int a = 0; a < 8; ++a)
                    #pragma unroll
                    for (int b2 = 0; b2 < 8; ++b2)
                        acc[a][b2] = fmaf(qa[a], ja[b2], acc[a][b2]);
            }
        }

        // epilogue: v = sq_j - 2*dot (ranking value; sq_q constant per row)
        float4 sj0 = *(const float4*)&sq32[bN + j0 + tx4];
        float4 sj1 = *(const float4*)&sq32[bN + j0 + 64 + tx4];
        #pragma unroll
        for (int ha = 0; ha < 2; ++ha) {
            __syncthreads();
            #pragma unroll
            for (int a = 0; a < 4; ++a) {
                int rl = ty4 + a;
                float4 v0, v1;
                v0.x = sj0.x - 2.f * acc[ha * 4 + a][0];
                v0.y = sj0.y - 2.f * acc[ha * 4 + a][1];
                v0.z = sj0.z - 2.f * acc[ha * 4 + a][2];
                v0.w = sj0.w - 2.f * acc[ha * 4 + a][3];
                v1.x = sj1.x - 2.f * acc[ha * 4 + a][4];
                v1.y = sj1.y - 2.f * acc[ha * 4 + a][5];
                v1.z = sj1.z - 2.f * acc[ha * 4 + a][6];
                v1.w = sj1.w - 2.f * acc[ha * 4 + a][7];
                *(float4*)&dt[rl][tx4]      = v0;
                *(float4*)&dt[rl][64 + tx4] = v1;
            }
            __syncthreads();
            // scan: thread q (=tid, <128) owns query q0+q; active in its pass
            if (tid < 128 && (tid >> 6) == ha) {
                int r = tid & 63;
                int q = tid;
                for (int jj = 0; jj < 128; ++jj) {
                    int j = (jj + r) & 127;          // stagger banks
                    float d = dt[r][j];
                    if (d < worst) {
                        topd[q][wpos] = d;
                        topi[q][wpos] = (unsigned short)(j0 + j);
                        float w2 = topd[q][0]; int wp2 = 0;
                        #pragma unroll
                        for (int s2 = 1; s2 < TOPC; ++s2) {
                            float tv = topd[q][s2];
                            if (tv > w2) { w2 = tv; wp2 = s2; }
                        }
                        worst = w2; wpos = wp2;
                    }
                }
            }
        }
    }

    if (tid < 128) {
        size_t base = ((size_t)(bN + q0 + tid)) * (8 * TOPC) + (size_t)s * TOPC;
        #pragma unroll
        for (int s2 = 0; s2 < TOPC; ++s2)
            cand_i[base + s2] = (int)topi[tid][s2];
    }
}

// ---------------- 5) fp64 re-rank of 160 candidates + weights ----------------
// block 256 = 32 points x 8 threads; grid 256
__global__ void merge_rerank(const int* __restrict__ cand_i,
                             const float* __restrict__ xt,
                             const double* __restrict__ sq64,
                             int* __restrict__ nidx, float* __restrict__ wgt) {
    __shared__ double d64[32][161];
    int tid = threadIdx.x;
    int pl = tid >> 3, c8 = tid & 7;
    int m = (blockIdx.x << 5) + pl;
    int b = m >> 12;
    const float* rm = xt + ((size_t)m << 8);
    size_t cbase = (size_t)m * 160 + (size_t)c8 * TOPC;
    for (int cc = 0; cc < TOPC; ++cc) {
        int j = cand_i[cbase + cc];
        int n = (b << 12) + j;
        const float* rn = xt + ((size_t)n << 8);
        double acc = 0.0;
        #pragma unroll 8
        for (int c = 0; c < C_; c += 4) {
            float4 a4 = *(const float4*)(rm + c);
            float4 b4 = *(const float4*)(rn + c);
            acc = fma((double)a4.x, (double)b4.x, acc);
            acc = fma((double)a4.y, (double)b4.y, acc);
            acc = fma((double)a4.z, (double)b4.z, acc);
            acc = fma((double)a4.w, (double)b4.w, acc);
        }
        d64[pl][c8 * TOPC + cc] = sq64[n] - 2.0 * acc;   // exact-rank value
    }
    __syncthreads();
    if (tid < 32) {
        int mm = (blockIdx.x << 5) + tid;
        int bb = mm >> 12;
        double td[K_]; int ti[K_];
        #pragma unroll
        for (int k = 0; k < K_; ++k) { td[k] = 1.0e300; ti[k] = 0; }
        size_t cb2 = (size_t)mm * 160;
        for (int cc = 0; cc < 160; ++cc) {
            double d = d64[tid][cc];
            int j = cand_i[cb2 + cc];
            #pragma unroll
            for (int s = 0; s < K_; ++s) {     // sorted bubble-insert, strict <
                bool lt = d < td[s];
                double od = td[s]; int oi = ti[s];
                td[s] = lt ? d : od;  ti[s] = lt ? j : oi;
                d = lt ? od : d;      j = lt ? oi : j;
            }
        }
        double sqm = sq64[mm];
        double rdm = sqrt(sqm);
        #pragma unroll
        for (int k = 0; k < K_; ++k) {
            int n = (bb << 12) + ti[k];
            double sqn = sq64[n];
            double dot = 0.5 * (sqn - td[k]);          // num = feat_n . feat_m
            double w = dot / (sqrt(sqn) * rdm);        // cosine similarity
            nidx[mm * K_ + k] = n;
            wgt[mm * K_ + k]  = (float)w;
        }
    }
}

// ---------------- 6) Y1 = feat@W1^T ; Y2 = feat@W2^T + b ----------------
// grid (32 ptiles, 4 octiles, 2 batches), block 256
#define YKC 32
__launch_bounds__(256, 2)
__global__ void y_kernel(const float* __restrict__ x, const float* __restrict__ Wt,
                         const float* __restrict__ bias,
                         float* __restrict__ Y1, float* __restrict__ Y2) {
    __shared__ float af[YKC][128];
    __shared__ float wf[YKC][128];   // cols 0..63: W1 chans, 64..127: W2 chans
    int p0  = blockIdx.x << 7;
    int oc0 = blockIdx.y << 6;
    int b   = blockIdx.z;
    const float* xb = x + ((size_t)b << 20);
    int tid = threadIdx.x, tx = tid & 15, ty = tid >> 4;
    int tx4 = tx << 2, ty4 = ty << 2;
    float acc[8][8];
    #pragma unroll
    for (int a = 0; a < 8; ++a)
        #pragma unroll
        for (int b2 = 0; b2 < 8; ++b2) acc[a][b2] = 0.f;

    for (int cc0 = 0; cc0 < C_; cc0 += YKC) {
        __syncthreads();
        for (int e = tid; e < YKC * 128; e += 256) {
            int d = e >> 7, q = e & 127;
            af[d][q] = xb[(size_t)(cc0 + d) * N_ + p0 + q];
            int row = (q < 64) ? (cc0 + d) : (C_ + cc0 + d);
            wf[d][q] = Wt[(size_t)row * C_ + oc0 + (q & 63)];
        }
        __syncthreads();
        #pragma unroll 8
        for (int d = 0; d < YKC; ++d) {
            float4 a0 = *(const float4*)&af[d][ty4];
            float4 a1 = *(const float4*)&af[d][64 + ty4];
            float4 w0 = *(const float4*)&wf[d][tx4];
            float4 w1 = *(const float4*)&wf[d][64 + tx4];
            float pa[8] = {a0.x, a0.y, a0.z, a0.w, a1.x, a1.y, a1.z, a1.w};
            float wa[8] = {w0.x, w0.y, w0.z, w0.w, w1.x, w1.y, w1.z, w1.w};
            #pragma unroll
            for (int a = 0; a < 8; ++a)
                #pragma unroll
                for (int b2 = 0; b2 < 8; ++b2)
                    acc[a][b2] = fmaf(pa[a], wa[b2], acc[a][b2]);
        }
    }
    float4 bv = *(const float4*)&bias[oc0 + tx4];
    #pragma unroll
    for (int ha = 0; ha < 2; ++ha) {
        #pragma unroll
        for (int a = 0; a < 4; ++a) {
            int pg = (b << 12) + p0 + ha * 64 + ty4 + a;
            float4 o1, o2;
            o1.x = acc[ha * 4 + a][0]; o1.y = acc[ha * 4 + a][1];
            o1.z = acc[ha * 4 + a][2]; o1.w = acc[ha * 4 + a][3];
            o2.x = acc[ha * 4 + a][4] + bv.x; o2.y = acc[ha * 4 + a][5] + bv.y;
            o2.z = acc[ha * 4 + a][6] + bv.z; o2.w = acc[ha * 4 + a][7] + bv.w;
            *(float4*)&Y1[(size_t)pg * C_ + oc0 + tx4] = o1;
            *(float4*)&Y2[(size_t)pg * C_ + oc0 + tx4] = o2;
        }
    }
}

// ---------------- 7) weighted max epilogue ----------------
__global__ void final_kernel(const float* __restrict__ Y1, const float* __restrict__ Y2,
                             const int* __restrict__ nidx, const float* __restrict__ wgt,
                             float* __restrict__ out) {
    __shared__ int   snk[K_];
    __shared__ float swt[K_];
    int m = blockIdx.x;
    int c = threadIdx.x;
    if (c < K_) { snk[c] = nidx[m * K_ + c]; swt[c] = wgt[m * K_ + c]; }
    __syncthreads();
    float y2 = Y2[((size_t)m << 8) + c];
    float acc = -3.0e38f;
    #pragma unroll
    for (int k = 0; k < K_; ++k) {
        float v = swt[k] * (Y1[((size_t)snk[k] << 8) + c] + y2);
        acc = fmaxf(acc, v);
    }
    int b = m >> 12, i = m & 4095;
    out[(((size_t)b << 8) + c) * N_ + i] = acc;
}

extern "C" void kernel_launch(void* const* d_in, const int* in_sizes, int n_in,
                              void* d_out, int out_size, void* d_ws, size_t ws_size,
                              hipStream_t stream) {
    const float* x    = (const float*)d_in[0];
    const float* W    = (const float*)d_in[1];
    const float* bias = (const float*)d_in[2];
    float* out = (float*)d_out;

    float* ws = (float*)d_ws;
    float*  sq32 = ws;                          // 8192
    double* sq64 = (double*)(ws + 8192);        // 8192 dbl (16384 f)
    float*  Wt   = ws + 24576;                  // 131072
    float*  xt   = ws + 155648;                 // 2097152
    float*  Y1   = ws + 2252800;                // 2097152
    float*  Y2   = ws + 4349952;                // 2097152
    float*  wgt  = ws + 6447104;                // 131072
    int*    nidx = (int*)(ws + 6578176);        // 131072 -> end 6709248 floats (26.8 MB)
    int*    candi = (int*)(ws + 2252800);       // alias Y1 region (consumed before Y written)

    sq_kernel<<<32, 256, 0, stream>>>(x, sq32, sq64);
    xt_kernel<<<dim3(64, 4, 2), 256, 0, stream>>>(x, xt);
    wt_kernel<<<dim3(8, 4, 1), 256, 0, stream>>>(W, Wt);
    dist_topk_kernel<<<dim3(32, 8, 2), 256, 0, stream>>>(x, sq32, candi);
    merge_rerank<<<256, 256, 0, stream>>>(candi, xt, sq64, nidx, wgt);
    y_kernel<<<dim3(32, 4, 2), 256, 0, stream>>>(x, Wt, bias, Y1, Y2);
    final_kernel<<<8192, 256, 0, stream>>>(Y1, Y2, nidx, wgt, out);
}

// Round 2
// 438.595 us; speedup vs baseline: 2.1425x; 2.1425x over previous
//
#include <hip/hip_runtime.h>

// NeighConv: B=2, C=256, N=4096, K=16
// Pipeline:
//  1) sq_kernel:     sq32[p], sq64[p] = ||x_p||^2
//  2) xt_kernel:     xt[p][c] fp32 + xh[p][c] fp16 (point-major features)
//  3) wt_kernel:     Wt[d][c] = W[c][d]
//  4) dist_kernel:   MFMA fp16 gram; V[i][j] = sq_j - 2*dot  (chunked over i)
//  5) select_kernel: exact per-query top-20 of V row (wave-parallel)
//  6) merge_rerank:  fp64 re-rank of 20 candidates -> true top-16 + cosine wgt
//  7) y_kernel:      Y1[p]=feat@W1^T, Y2[p]=feat@W2^T + b
//  8) final_kernel:  out[b][c][i] = max_k w_k*(Y1[nk][c]+Y2[m][c])

#define B_ 2
#define C_ 256
#define N_ 4096
#define K_ 16
#define CAND 20
#define INF_F 3.0e38f

typedef _Float16 f16x8 __attribute__((ext_vector_type(8)));
typedef float    f32x4 __attribute__((ext_vector_type(4)));

// ---------------- 1) squared norms ----------------
__global__ void sq_kernel(const float* __restrict__ x,
                          float* __restrict__ sq32, double* __restrict__ sq64) {
    int p = blockIdx.x * 256 + threadIdx.x;           // 0..8191
    int b = p >> 12, i = p & 4095;
    const float* xb = x + ((size_t)b << 20) + i;
    double acc = 0.0;
    #pragma unroll 8
    for (int c = 0; c < C_; ++c) {
        double v = (double)xb[(size_t)c << 12];
        acc = fma(v, v, acc);
    }
    sq64[p] = acc;
    sq32[p] = (float)acc;
}

// ---------------- 2) transpose x -> xt fp32 + xh fp16 ----------------
__global__ void xt_kernel(const float* __restrict__ x, float* __restrict__ xt,
                          _Float16* __restrict__ xh) {
    __shared__ float tile[64][65];
    int i0 = blockIdx.x * 64;
    int c0 = blockIdx.y * 64;
    int b  = blockIdx.z;
    const float* xb = x + ((size_t)b << 20);
    int tid = threadIdx.x;
    int tx = tid & 63, tyy = tid >> 6;
    for (int r = tyy; r < 64; r += 4)
        tile[r][tx] = xb[(size_t)(c0 + r) * N_ + i0 + tx];
    __syncthreads();
    float*    xtb = xt + ((size_t)b << 20);
    _Float16* xhb = xh + ((size_t)b << 20);
    for (int r = tyy; r < 64; r += 4) {
        float v = tile[tx][r];
        xtb[(size_t)(i0 + r) * C_ + c0 + tx] = v;
        xhb[(size_t)(i0 + r) * C_ + c0 + tx] = (_Float16)v;
    }
}

// ---------------- 3) transpose W -> Wt[d][c] ----------------
__global__ void wt_kernel(const float* __restrict__ W, float* __restrict__ Wt) {
    __shared__ float tile[64][65];
    int d0 = blockIdx.x * 64;
    int c0 = blockIdx.y * 64;
    int tid = threadIdx.x;
    int tx = tid & 63, tyy = tid >> 6;
    for (int r = tyy; r < 64; r += 4)
        tile[r][tx] = W[(size_t)(c0 + r) * 512 + d0 + tx];
    __syncthreads();
    for (int r = tyy; r < 64; r += 4)
        Wt[(size_t)(d0 + r) * C_ + c0 + tx] = tile[tx][r];
}

// ---------------- 4) MFMA distance kernel ----------------
// block 256 = 4 waves (2x2 of 64x64). tile 128(i) x 128(j).
// A = queries (rows), B = j-points (cols); both frags loaded identically from
// xh[point][c] (same per-lane (point,k) mapping on both sides -> any k
// permutation cancels). C/D: col=lane&15, row=(lane>>4)*4+reg.
__launch_bounds__(256)
__global__ void dist_kernel(const _Float16* __restrict__ xh,
                            const float* __restrict__ sq32,
                            float* __restrict__ Vc, int b, int i0base) {
    int jt = blockIdx.x, it = blockIdx.y;
    int tid = threadIdx.x;
    int w = tid >> 6, l = tid & 63;
    int wr = w >> 1, wc = w & 1;
    int lr = l & 15, lg = l >> 4;
    const _Float16* xb = xh + ((size_t)b << 20);
    int irow = i0base + it * 128 + wr * 64 + lr;
    int jrow = jt * 128 + wc * 64 + lr;
    const _Float16* aptr = xb + (size_t)irow * C_ + lg * 8;
    const _Float16* bptr = xb + (size_t)jrow * C_ + lg * 8;

    f32x4 acc[4][4];
    #pragma unroll
    for (int mi = 0; mi < 4; ++mi)
        #pragma unroll
        for (int ni = 0; ni < 4; ++ni)
            acc[mi][ni] = (f32x4){0.f, 0.f, 0.f, 0.f};

    #pragma unroll
    for (int ks = 0; ks < 8; ++ks) {
        f16x8 af[4], bf[4];
        #pragma unroll
        for (int mi = 0; mi < 4; ++mi)
            af[mi] = *(const f16x8*)(aptr + (size_t)mi * 16 * C_ + ks * 32);
        #pragma unroll
        for (int ni = 0; ni < 4; ++ni)
            bf[ni] = *(const f16x8*)(bptr + (size_t)ni * 16 * C_ + ks * 32);
        #pragma unroll
        for (int mi = 0; mi < 4; ++mi)
            #pragma unroll
            for (int ni = 0; ni < 4; ++ni)
                acc[mi][ni] = __builtin_amdgcn_mfma_f32_16x16x32_f16(
                    af[mi], bf[ni], acc[mi][ni], 0, 0, 0);
    }

    int bN = b << 12;
    #pragma unroll
    for (int ni = 0; ni < 4; ++ni) {
        int jg = jt * 128 + wc * 64 + ni * 16 + lr;
        float sj = sq32[bN + jg];
        #pragma unroll
        for (int mi = 0; mi < 4; ++mi) {
            int iml = it * 128 + wr * 64 + mi * 16 + lg * 4;  // chunk-local row
            #pragma unroll
            for (int r = 0; r < 4; ++r)
                Vc[(size_t)(iml + r) * (size_t)N_ + jg] = sj - 2.0f * acc[mi][ni][r];
        }
    }
}

// ---------------- 5) exact wave-parallel top-20 ----------------
__device__ __forceinline__ void ins3(float v, int j,
                                     float& v0, float& v1, float& v2,
                                     int& j0, int& j1, int& j2) {
    if (v < v2) {
        if (v < v1) {
            v2 = v1; j2 = j1;
            if (v < v0) { v1 = v0; j1 = j0; v0 = v; j0 = j; }
            else        { v1 = v;  j1 = j; }
        } else { v2 = v; j2 = j; }
    }
}

__global__ void select_kernel(const float* __restrict__ Vc,
                              int* __restrict__ cand, int m0) {
    int tid = threadIdx.x;
    int wv = tid >> 6, l = tid & 63;
    int ml = blockIdx.x * 4 + wv;                 // chunk-local query row
    const float* row = Vc + (size_t)ml * (size_t)N_;
    int lbase = l << 2;

    float v0 = INF_F, v1 = INF_F, v2 = INF_F;
    int j0 = -1, j1 = -1, j2 = -1;
    unsigned long long taken = 0ULL;

    for (int t = 0; t < 16; ++t) {
        float4 f = *(const float4*)(row + t * 256 + lbase);
        #pragma unroll
        for (int q = 0; q < 4; ++q) {
            float v = (&f.x)[q];
            ins3(v, t * 256 + lbase + q, v0, v1, v2, j0, j1, j2);
        }
    }

    int mycand = -1;
    for (int r = 0; r < CAND; ++r) {
        float mv = v0; int mj = j0;
        #pragma unroll
        for (int s = 1; s < 64; s <<= 1) {
            float ov = __shfl_xor(mv, s);
            int   oj = __shfl_xor(mj, s);
            if (ov < mv || (ov == mv && oj < mj)) { mv = ov; mj = oj; }
        }
        if (l == r) mycand = mj;
        if (j0 == mj) {                           // owner pops (j unique)
            int slot = ((mj >> 8) << 2) | (mj & 3);
            taken |= (1ULL << slot);
            v0 = v1; j0 = j1; v1 = v2; j1 = j2; v2 = INF_F; j2 = -1;
            if (j0 < 0) {                         // refill (rare, exact)
                v0 = v1 = v2 = INF_F; j0 = j1 = j2 = -1;
                for (int t = 0; t < 16; ++t) {
                    float4 f = *(const float4*)(row + t * 256 + lbase);
                    #pragma unroll
                    for (int q = 0; q < 4; ++q) {
                        int sl = t * 4 + q;
                        if ((taken >> sl) & 1ULL) continue;
                        float v = (&f.x)[q];
                        ins3(v, t * 256 + lbase + q, v0, v1, v2, j0, j1, j2);
                    }
                }
            }
        }
    }
    if (l < CAND)
        cand[(size_t)(m0 + ml) * CAND + l] = mycand;
}

// ---------------- 6) fp64 re-rank of 20 candidates + weights ----------------
__global__ void merge_rerank(const int* __restrict__ cand,
                             const float* __restrict__ xt,
                             const double* __restrict__ sq64,
                             int* __restrict__ nidx, float* __restrict__ wgt) {
    __shared__ double d64[64][CAND + 1];
    int tid = threadIdx.x;
    int pl = tid >> 2, c4 = tid & 3;              // 64 points x 4 threads
    int m = (blockIdx.x << 6) + pl;
    int b = m >> 12;
    const float* rm = xt + ((size_t)m << 8);
    for (int u = 0; u < 5; ++u) {
        int cc = c4 * 5 + u;
        int j = cand[(size_t)m * CAND + cc];
        int n = (b << 12) + j;
        const float* rn = xt + ((size_t)n << 8);
        double acc = 0.0;
        #pragma unroll 8
        for (int c = 0; c < C_; c += 4) {
            float4 a4 = *(const float4*)(rm + c);
            float4 b4 = *(const float4*)(rn + c);
            acc = fma((double)a4.x, (double)b4.x, acc);
            acc = fma((double)a4.y, (double)b4.y, acc);
            acc = fma((double)a4.z, (double)b4.z, acc);
            acc = fma((double)a4.w, (double)b4.w, acc);
        }
        d64[pl][cc] = sq64[n] - 2.0 * acc;
    }
    __syncthreads();
    if (tid < 64) {
        int mm = (blockIdx.x << 6) + tid;
        int bb = mm >> 12;
        double td[K_]; int ti[K_];
        #pragma unroll
        for (int k = 0; k < K_; ++k) { td[k] = 1.0e300; ti[k] = 0; }
        for (int cc = 0; cc < CAND; ++cc) {
            double d = d64[tid][cc];
            int j = cand[(size_t)mm * CAND + cc];
            #pragma unroll
            for (int s = 0; s < K_; ++s) {        // sorted bubble-insert, strict <
                bool lt = d < td[s];
                double od = td[s]; int oi = ti[s];
                td[s] = lt ? d : od;  ti[s] = lt ? j : oi;
                d = lt ? od : d;      j = lt ? oi : j;
            }
        }
        double sqm = sq64[mm];
        double rdm = sqrt(sqm);
        #pragma unroll
        for (int k = 0; k < K_; ++k) {
            int n = (bb << 12) + ti[k];
            double sqn = sq64[n];
            double dot = 0.5 * (sqn - td[k]);
            double w = dot / (sqrt(sqn) * rdm);
            nidx[mm * K_ + k] = n;
            wgt[mm * K_ + k]  = (float)w;
        }
    }
}

// ---------------- 7) Y1 = feat@W1^T ; Y2 = feat@W2^T + b ----------------
#define YKC 32
__launch_bounds__(256, 2)
__global__ void y_kernel(const float* __restrict__ x, const float* __restrict__ Wt,
                         const float* __restrict__ bias,
                         float* __restrict__ Y1, float* __restrict__ Y2) {
    __shared__ float af[YKC][128];
    __shared__ float wf[YKC][128];
    int p0  = blockIdx.x << 7;
    int oc0 = blockIdx.y << 6;
    int b   = blockIdx.z;
    const float* xb = x + ((size_t)b << 20);
    int tid = threadIdx.x, tx = tid & 15, ty = tid >> 4;
    int tx4 = tx << 2, ty4 = ty << 2;
    float acc[8][8];
    #pragma unroll
    for (int a = 0; a < 8; ++a)
        #pragma unroll
        for (int b2 = 0; b2 < 8; ++b2) acc[a][b2] = 0.f;

    for (int cc0 = 0; cc0 < C_; cc0 += YKC) {
        __syncthreads();
        for (int e = tid; e < YKC * 128; e += 256) {
            int d = e >> 7, q = e & 127;
            af[d][q] = xb[(size_t)(cc0 + d) * N_ + p0 + q];
            int row = (q < 64) ? (cc0 + d) : (C_ + cc0 + d);
            wf[d][q] = Wt[(size_t)row * C_ + oc0 + (q & 63)];
        }
        __syncthreads();
        #pragma unroll 8
        for (int d = 0; d < YKC; ++d) {
            float4 a0 = *(const float4*)&af[d][ty4];
            float4 a1 = *(const float4*)&af[d][64 + ty4];
            float4 w0 = *(const float4*)&wf[d][tx4];
            float4 w1 = *(const float4*)&wf[d][64 + tx4];
            float pa[8] = {a0.x, a0.y, a0.z, a0.w, a1.x, a1.y, a1.z, a1.w};
            float wa[8] = {w0.x, w0.y, w0.z, w0.w, w1.x, w1.y, w1.z, w1.w};
            #pragma unroll
            for (int a = 0; a < 8; ++a)
                #pragma unroll
                for (int b2 = 0; b2 < 8; ++b2)
                    acc[a][b2] = fmaf(pa[a], wa[b2], acc[a][b2]);
        }
    }
    float4 bv = *(const float4*)&bias[oc0 + tx4];
    #pragma unroll
    for (int ha = 0; ha < 2; ++ha) {
        #pragma unroll
        for (int a = 0; a < 4; ++a) {
            int pg = (b << 12) + p0 + ha * 64 + ty4 + a;
            float4 o1, o2;
            o1.x = acc[ha * 4 + a][0]; o1.y = acc[ha * 4 + a][1];
            o1.z = acc[ha * 4 + a][2]; o1.w = acc[ha * 4 + a][3];
            o2.x = acc[ha * 4 + a][4] + bv.x; o2.y = acc[ha * 4 + a][5] + bv.y;
            o2.z = acc[ha * 4 + a][6] + bv.z; o2.w = acc[ha * 4 + a][7] + bv.w;
            *(float4*)&Y1[(size_t)pg * C_ + oc0 + tx4] = o1;
            *(float4*)&Y2[(size_t)pg * C_ + oc0 + tx4] = o2;
        }
    }
}

// ---------------- 8) weighted max epilogue ----------------
__global__ void final_kernel(const float* __restrict__ Y1, const float* __restrict__ Y2,
                             const int* __restrict__ nidx, const float* __restrict__ wgt,
                             float* __restrict__ out) {
    __shared__ int   snk[K_];
    __shared__ float swt[K_];
    int m = blockIdx.x;
    int c = threadIdx.x;
    if (c < K_) { snk[c] = nidx[m * K_ + c]; swt[c] = wgt[m * K_ + c]; }
    __syncthreads();
    float y2 = Y2[((size_t)m << 8) + c];
    float acc = -INF_F;
    #pragma unroll
    for (int k = 0; k < K_; ++k) {
        float v = swt[k] * (Y1[((size_t)snk[k] << 8) + c] + y2);
        acc = fmaxf(acc, v);
    }
    int b = m >> 12, i = m & 4095;
    out[(((size_t)b << 8) + c) * N_ + i] = acc;
}

extern "C" void kernel_launch(void* const* d_in, const int* in_sizes, int n_in,
                              void* d_out, int out_size, void* d_ws, size_t ws_size,
                              hipStream_t stream) {
    const float* x    = (const float*)d_in[0];
    const float* W    = (const float*)d_in[1];
    const float* bias = (const float*)d_in[2];
    float* out = (float*)d_out;

    float* ws = (float*)d_ws;
    size_t off = 0;
    float*  sq32 = ws + off;           off += 8192;
    double* sq64 = (double*)(ws + off); off += 16384;
    float*  Wt   = ws + off;           off += 131072;
    float*  wgt  = ws + off;           off += 131072;
    int*    nidx = (int*)(ws + off);   off += 131072;
    float*  xt   = ws + off;           off += 2097152;   // 2M floats
    size_t reuse0 = off;                                  // dead after merge:
    _Float16* xh = (_Float16*)(ws + off); off += 1048576; // 2M halves
    int*    cand = (int*)(ws + off);   off += 163840;     // 8192*20 ints
    size_t vstart = off;
    float*  Vc   = ws + vstart;
    float*  Y1   = ws + reuse0;                           // reuses xh/cand/V
    float*  Y2   = Y1 + 2097152;

    // choose chunk count so V-chunk fits in remaining workspace
    size_t avail = ws_size / 4 > vstart ? ws_size / 4 - vstart : 0;
    int nch = 2;                                          // chunks never cross batch
    while (nch < 64 && (size_t)(33554432u / nch) > avail) nch <<= 1;
    int cq = 8192 / nch;                                  // queries per chunk

    sq_kernel<<<32, 256, 0, stream>>>(x, sq32, sq64);
    xt_kernel<<<dim3(64, 4, 2), 256, 0, stream>>>(x, xt, xh);
    wt_kernel<<<dim3(8, 4, 1), 256, 0, stream>>>(W, Wt);

    for (int c = 0; c < nch; ++c) {
        int m0 = c * cq;
        int b = m0 >> 12;
        int i0base = m0 & 4095;
        dist_kernel<<<dim3(32, cq / 128, 1), 256, 0, stream>>>(xh, sq32, Vc, b, i0base);
        select_kernel<<<dim3(cq / 4, 1, 1), 256, 0, stream>>>(Vc, cand, m0);
    }

    merge_rerank<<<128, 256, 0, stream>>>(cand, xt, sq64, nidx, wgt);
    y_kernel<<<dim3(32, 4, 2), 256, 0, stream>>>(x, Wt, bias, Y1, Y2);
    final_kernel<<<8192, 256, 0, stream>>>(Y1, Y2, nidx, wgt, out);
}

// Round 3
// 311.678 us; speedup vs baseline: 3.0149x; 1.4072x over previous
//
#include <hip/hip_runtime.h>

// NeighConv: B=2, C=256, N=4096, K=16
// Pipeline:
//  1) sq_kernel:     sq32[p], sq64[p] = ||x_p||^2
//  2) xt_kernel:     xt[p][c] fp32 + xh[p][c] fp16 (point-major features)
//  3) wt_kernel:     Wt[d][c] = W[c][d]
//  4) dist_kernel:   MFMA fp16 gram; V[i][j] = sq_j - 2*dot  (chunked over i)
//  5) select2:       exact per-query top-20 via rank-count (wave-parallel)
//  6) merge_rerank:  fp64 re-rank of 20 candidates -> true top-16 + cosine wgt
//  7) y_kernel:      Y1[p]=feat@W1^T, Y2[p]=feat@W2^T + b
//  8) final_kernel:  out[b][c][i] = max_k w_k*(Y1[nk][c]+Y2[m][c])

#define B_ 2
#define C_ 256
#define N_ 4096
#define K_ 16
#define CAND 20
#define INF_F 3.0e38f

typedef _Float16 f16x8 __attribute__((ext_vector_type(8)));
typedef float    f32x4 __attribute__((ext_vector_type(4)));

// ---------------- 1) squared norms ----------------
__global__ void sq_kernel(const float* __restrict__ x,
                          float* __restrict__ sq32, double* __restrict__ sq64) {
    int p = blockIdx.x * 256 + threadIdx.x;           // 0..8191
    int b = p >> 12, i = p & 4095;
    const float* xb = x + ((size_t)b << 20) + i;
    double acc = 0.0;
    #pragma unroll 8
    for (int c = 0; c < C_; ++c) {
        double v = (double)xb[(size_t)c << 12];
        acc = fma(v, v, acc);
    }
    sq64[p] = acc;
    sq32[p] = (float)acc;
}

// ---------------- 2) transpose x -> xt fp32 + xh fp16 ----------------
__global__ void xt_kernel(const float* __restrict__ x, float* __restrict__ xt,
                          _Float16* __restrict__ xh) {
    __shared__ float tile[64][65];
    int i0 = blockIdx.x * 64;
    int c0 = blockIdx.y * 64;
    int b  = blockIdx.z;
    const float* xb = x + ((size_t)b << 20);
    int tid = threadIdx.x;
    int tx = tid & 63, tyy = tid >> 6;
    for (int r = tyy; r < 64; r += 4)
        tile[r][tx] = xb[(size_t)(c0 + r) * N_ + i0 + tx];
    __syncthreads();
    float*    xtb = xt + ((size_t)b << 20);
    _Float16* xhb = xh + ((size_t)b << 20);
    for (int r = tyy; r < 64; r += 4) {
        float v = tile[tx][r];
        xtb[(size_t)(i0 + r) * C_ + c0 + tx] = v;
        xhb[(size_t)(i0 + r) * C_ + c0 + tx] = (_Float16)v;
    }
}

// ---------------- 3) transpose W -> Wt[d][c] ----------------
__global__ void wt_kernel(const float* __restrict__ W, float* __restrict__ Wt) {
    __shared__ float tile[64][65];
    int d0 = blockIdx.x * 64;
    int c0 = blockIdx.y * 64;
    int tid = threadIdx.x;
    int tx = tid & 63, tyy = tid >> 6;
    for (int r = tyy; r < 64; r += 4)
        tile[r][tx] = W[(size_t)(c0 + r) * 512 + d0 + tx];
    __syncthreads();
    for (int r = tyy; r < 64; r += 4)
        Wt[(size_t)(d0 + r) * C_ + c0 + tx] = tile[tx][r];
}

// ---------------- 4) MFMA distance kernel ----------------
__launch_bounds__(256)
__global__ void dist_kernel(const _Float16* __restrict__ xh,
                            const float* __restrict__ sq32,
                            float* __restrict__ Vc, int b, int i0base) {
    int jt = blockIdx.x, it = blockIdx.y;
    int tid = threadIdx.x;
    int w = tid >> 6, l = tid & 63;
    int wr = w >> 1, wc = w & 1;
    int lr = l & 15, lg = l >> 4;
    const _Float16* xb = xh + ((size_t)b << 20);
    int irow = i0base + it * 128 + wr * 64 + lr;
    int jrow = jt * 128 + wc * 64 + lr;
    const _Float16* aptr = xb + (size_t)irow * C_ + lg * 8;
    const _Float16* bptr = xb + (size_t)jrow * C_ + lg * 8;

    f32x4 acc[4][4];
    #pragma unroll
    for (int mi = 0; mi < 4; ++mi)
        #pragma unroll
        for (int ni = 0; ni < 4; ++ni)
            acc[mi][ni] = (f32x4){0.f, 0.f, 0.f, 0.f};

    #pragma unroll
    for (int ks = 0; ks < 8; ++ks) {
        f16x8 af[4], bf[4];
        #pragma unroll
        for (int mi = 0; mi < 4; ++mi)
            af[mi] = *(const f16x8*)(aptr + (size_t)mi * 16 * C_ + ks * 32);
        #pragma unroll
        for (int ni = 0; ni < 4; ++ni)
            bf[ni] = *(const f16x8*)(bptr + (size_t)ni * 16 * C_ + ks * 32);
        #pragma unroll
        for (int mi = 0; mi < 4; ++mi)
            #pragma unroll
            for (int ni = 0; ni < 4; ++ni)
                acc[mi][ni] = __builtin_amdgcn_mfma_f32_16x16x32_f16(
                    af[mi], bf[ni], acc[mi][ni], 0, 0, 0);
    }

    int bN = b << 12;
    #pragma unroll
    for (int ni = 0; ni < 4; ++ni) {
        int jg = jt * 128 + wc * 64 + ni * 16 + lr;
        float sj = sq32[bN + jg];
        #pragma unroll
        for (int mi = 0; mi < 4; ++mi) {
            int iml = it * 128 + wr * 64 + mi * 16 + lg * 4;  // chunk-local row
            #pragma unroll
            for (int r = 0; r < 4; ++r)
                Vc[(size_t)(iml + r) * (size_t)N_ + jg] = sj - 2.0f * acc[mi][ni][r];
        }
    }
}

// ---------------- 5) exact top-20 via rank-count ----------------
// block 256 = 4 waves, one query per wave. Exact in lex (v,j) order.
__global__ void select2_kernel(const float* __restrict__ Vc,
                               int* __restrict__ cand, int m0) {
    __shared__ float sv0[4][64];
    __shared__ int   sj0[4][64];
    __shared__ float sval[4][256];
    __shared__ int   sidx[4][256];
    __shared__ float smv[4];
    __shared__ int   smj[4];

    int tid = threadIdx.x;
    int wv = tid >> 6, l = tid & 63;
    int ml = blockIdx.x * 4 + wv;                 // chunk-local query row
    const float* row = Vc + (size_t)ml * (size_t)N_;
    int lbase = l << 2;

    // load entire row slice (16 outstanding float4 loads/lane)
    float4 f[16];
    #pragma unroll
    for (int t = 0; t < 16; ++t)
        f[t] = *(const float4*)(row + t * 256 + lbase);

    // per-lane sorted top-4 (ascending, strict < keeps lex (v,j) order)
    float v0 = INF_F, v1 = INF_F, v2 = INF_F, v3 = INF_F;
    int j0 = -1, j1 = -1, j2 = -1, j3 = -1;
    #pragma unroll
    for (int t = 0; t < 16; ++t) {
        #pragma unroll
        for (int q = 0; q < 4; ++q) {
            float v = (&f[t].x)[q];
            int   j = t * 256 + lbase + q;
            if (v < v3) {
                v3 = v; j3 = j;
                if (v3 < v2) { float a = v2; v2 = v3; v3 = a; int c = j2; j2 = j3; j3 = c; }
                if (v2 < v1) { float a = v1; v1 = v2; v2 = a; int c = j1; j1 = j2; j2 = c; }
                if (v1 < v0) { float a = v0; v0 = v1; v1 = a; int c = j0; j0 = j1; j1 = c; }
            }
        }
    }

    // bound m = 20th-smallest of the 64 lane minima (valid upper bound on d20)
    sv0[wv][l] = v0; sj0[wv][l] = j0;
    __syncthreads();
    int r0 = 0;
    for (int o = 0; o < 64; ++o) {
        float ov = sv0[wv][o]; int oj = sj0[wv][o];
        r0 += (ov < v0) || (ov == v0 && oj < j0);
    }
    if (r0 == 19) { smv[wv] = v0; smj[wv] = j0; }
    __syncthreads();
    float mv = smv[wv]; int mj = smj[wv];

    // candidate filter: (v,j) <=lex (mv,mj)
    int c0 = (v0 < mv) || (v0 == mv && j0 <= mj);
    int c1 = (v1 < mv) || (v1 == mv && j1 <= mj);
    int c2 = (v2 < mv) || (v2 == mv && j2 <= mj);
    int c3 = (v3 < mv) || (v3 == mv && j3 <= mj);
    int cnt = c0 + c1 + c2 + c3;
    unsigned long long fb = __ballot(c3);     // 4th kept passes -> hidden 5th possible

    // wave prefix sum -> compact survivors to LDS
    int off = cnt;
    #pragma unroll
    for (int s = 1; s < 64; s <<= 1) {
        int n = __shfl_up(off, s);
        if (l >= s) off += n;
    }
    int tot = __shfl(off, 63);
    int pos = off - cnt;
    if (c0) { sval[wv][pos] = v0; sidx[wv][pos] = j0; ++pos; }
    if (c1) { sval[wv][pos] = v1; sidx[wv][pos] = j1; ++pos; }
    if (c2) { sval[wv][pos] = v2; sidx[wv][pos] = j2; ++pos; }
    if (c3) { sval[wv][pos] = v3; sidx[wv][pos] = j3; ++pos; }
    __syncthreads();

    if (fb == 0ULL) {
        // rank-count among survivors (superset of true top-20, global ranks)
        for (int p = l; p < tot; p += 64) {
            float v = sval[wv][p]; int j = sidx[wv][p];
            int r = 0;
            for (int o = 0; o < tot; ++o) {
                float ov = sval[wv][o]; int oj = sidx[wv][o];
                r += (ov < v) || (ov == v && oj < j);
            }
            if (r < CAND) cand[(size_t)(m0 + ml) * CAND + r] = j;
        }
    } else {
        // exact sequential extraction fallback (rare)
        unsigned long long taken = 0ULL;
        int mycand = -1;
        for (int r = 0; r < CAND; ++r) {
            float bv = v0; int bj = j0;
            #pragma unroll
            for (int s = 1; s < 64; s <<= 1) {
                float ov = __shfl_xor(bv, s);
                int   oj = __shfl_xor(bj, s);
                if (ov < bv || (ov == bv && oj < bj)) { bv = ov; bj = oj; }
            }
            if (l == r) mycand = bj;
            if (j0 == bj) {                       // owner pops (j unique)
                int slot = ((bj >> 8) << 2) | (bj & 3);
                taken |= (1ULL << slot);
                v0 = v1; j0 = j1; v1 = v2; j1 = j2; v2 = v3; j2 = j3;
                v3 = INF_F; j3 = -1;
                if (j0 < 0) {                     // refill from registers
                    v0 = v1 = v2 = v3 = INF_F; j0 = j1 = j2 = j3 = -1;
                    #pragma unroll
                    for (int t = 0; t < 16; ++t) {
                        #pragma unroll
                        for (int q = 0; q < 4; ++q) {
                            int sl = t * 4 + q;
                            if ((taken >> sl) & 1ULL) continue;
                            float v = (&f[t].x)[q];
                            int   j = t * 256 + lbase + q;
                            if (v < v3) {
                                v3 = v; j3 = j;
                                if (v3 < v2) { float a = v2; v2 = v3; v3 = a; int c = j2; j2 = j3; j3 = c; }
                                if (v2 < v1) { float a = v1; v1 = v2; v2 = a; int c = j1; j1 = j2; j2 = c; }
                                if (v1 < v0) { float a = v0; v0 = v1; v1 = a; int c = j0; j0 = j1; j1 = c; }
                            }
                        }
                    }
                }
            }
        }
        if (l < CAND) cand[(size_t)(m0 + ml) * CAND + l] = mycand;
    }
}

// ---------------- 6) fp64 re-rank of 20 candidates + weights ----------------
__global__ void merge_rerank(const int* __restrict__ cand,
                             const float* __restrict__ xt,
                             const double* __restrict__ sq64,
                             int* __restrict__ nidx, float* __restrict__ wgt) {
    __shared__ double d64[64][CAND + 1];
    int tid = threadIdx.x;
    int pl = tid >> 2, c4 = tid & 3;              // 64 points x 4 threads
    int m = (blockIdx.x << 6) + pl;
    int b = m >> 12;
    const float* rm = xt + ((size_t)m << 8);
    for (int u = 0; u < 5; ++u) {
        int cc = c4 * 5 + u;
        int j = cand[(size_t)m * CAND + cc];
        int n = (b << 12) + j;
        const float* rn = xt + ((size_t)n << 8);
        double acc = 0.0;
        #pragma unroll 8
        for (int c = 0; c < C_; c += 4) {
            float4 a4 = *(const float4*)(rm + c);
            float4 b4 = *(const float4*)(rn + c);
            acc = fma((double)a4.x, (double)b4.x, acc);
            acc = fma((double)a4.y, (double)b4.y, acc);
            acc = fma((double)a4.z, (double)b4.z, acc);
            acc = fma((double)a4.w, (double)b4.w, acc);
        }
        d64[pl][cc] = sq64[n] - 2.0 * acc;
    }
    __syncthreads();
    if (tid < 64) {
        int mm = (blockIdx.x << 6) + tid;
        int bb = mm >> 12;
        double td[K_]; int ti[K_];
        #pragma unroll
        for (int k = 0; k < K_; ++k) { td[k] = 1.0e300; ti[k] = 0; }
        for (int cc = 0; cc < CAND; ++cc) {
            double d = d64[tid][cc];
            int j = cand[(size_t)mm * CAND + cc];
            #pragma unroll
            for (int s = 0; s < K_; ++s) {        // sorted bubble-insert, strict <
                bool lt = d < td[s];
                double od = td[s]; int oi = ti[s];
                td[s] = lt ? d : od;  ti[s] = lt ? j : oi;
                d = lt ? od : d;      j = lt ? oi : j;
            }
        }
        double sqm = sq64[mm];
        double rdm = sqrt(sqm);
        #pragma unroll
        for (int k = 0; k < K_; ++k) {
            int n = (bb << 12) + ti[k];
            double sqn = sq64[n];
            double dot = 0.5 * (sqn - td[k]);
            double w = dot / (sqrt(sqn) * rdm);
            nidx[mm * K_ + k] = n;
            wgt[mm * K_ + k]  = (float)w;
        }
    }
}

// ---------------- 7) Y1 = feat@W1^T ; Y2 = feat@W2^T + b ----------------
#define YKC 32
__launch_bounds__(256, 2)
__global__ void y_kernel(const float* __restrict__ x, const float* __restrict__ Wt,
                         const float* __restrict__ bias,
                         float* __restrict__ Y1, float* __restrict__ Y2) {
    __shared__ float af[YKC][128];
    __shared__ float wf[YKC][128];
    int p0  = blockIdx.x << 7;
    int oc0 = blockIdx.y << 6;
    int b   = blockIdx.z;
    const float* xb = x + ((size_t)b << 20);
    int tid = threadIdx.x, tx = tid & 15, ty = tid >> 4;
    int tx4 = tx << 2, ty4 = ty << 2;
    float acc[8][8];
    #pragma unroll
    for (int a = 0; a < 8; ++a)
        #pragma unroll
        for (int b2 = 0; b2 < 8; ++b2) acc[a][b2] = 0.f;

    for (int cc0 = 0; cc0 < C_; cc0 += YKC) {
        __syncthreads();
        for (int e = tid; e < YKC * 128; e += 256) {
            int d = e >> 7, q = e & 127;
            af[d][q] = xb[(size_t)(cc0 + d) * N_ + p0 + q];
            int row = (q < 64) ? (cc0 + d) : (C_ + cc0 + d);
            wf[d][q] = Wt[(size_t)row * C_ + oc0 + (q & 63)];
        }
        __syncthreads();
        #pragma unroll 8
        for (int d = 0; d < YKC; ++d) {
            float4 a0 = *(const float4*)&af[d][ty4];
            float4 a1 = *(const float4*)&af[d][64 + ty4];
            float4 w0 = *(const float4*)&wf[d][tx4];
            float4 w1 = *(const float4*)&wf[d][64 + tx4];
            float pa[8] = {a0.x, a0.y, a0.z, a0.w, a1.x, a1.y, a1.z, a1.w};
            float wa[8] = {w0.x, w0.y, w0.z, w0.w, w1.x, w1.y, w1.z, w1.w};
            #pragma unroll
            for (int a = 0; a < 8; ++a)
                #pragma unroll
                for (int b2 = 0; b2 < 8; ++b2)
                    acc[a][b2] = fmaf(pa[a], wa[b2], acc[a][b2]);
        }
    }
    float4 bv = *(const float4*)&bias[oc0 + tx4];
    #pragma unroll
    for (int ha = 0; ha < 2; ++ha) {
        #pragma unroll
        for (int a = 0; a < 4; ++a) {
            int pg = (b << 12) + p0 + ha * 64 + ty4 + a;
            float4 o1, o2;
            o1.x = acc[ha * 4 + a][0]; o1.y = acc[ha * 4 + a][1];
            o1.z = acc[ha * 4 + a][2]; o1.w = acc[ha * 4 + a][3];
            o2.x = acc[ha * 4 + a][4] + bv.x; o2.y = acc[ha * 4 + a][5] + bv.y;
            o2.z = acc[ha * 4 + a][6] + bv.z; o2.w = acc[ha * 4 + a][7] + bv.w;
            *(float4*)&Y1[(size_t)pg * C_ + oc0 + tx4] = o1;
            *(float4*)&Y2[(size_t)pg * C_ + oc0 + tx4] = o2;
        }
    }
}

// ---------------- 8) weighted max epilogue ----------------
__global__ void final_kernel(const float* __restrict__ Y1, const float* __restrict__ Y2,
                             const int* __restrict__ nidx, const float* __restrict__ wgt,
                             float* __restrict__ out) {
    __shared__ int   snk[K_];
    __shared__ float swt[K_];
    int m = blockIdx.x;
    int c = threadIdx.x;
    if (c < K_) { snk[c] = nidx[m * K_ + c]; swt[c] = wgt[m * K_ + c]; }
    __syncthreads();
    float y2 = Y2[((size_t)m << 8) + c];
    float acc = -INF_F;
    #pragma unroll
    for (int k = 0; k < K_; ++k) {
        float v = swt[k] * (Y1[((size_t)snk[k] << 8) + c] + y2);
        acc = fmaxf(acc, v);
    }
    int b = m >> 12, i = m & 4095;
    out[(((size_t)b << 8) + c) * N_ + i] = acc;
}

extern "C" void kernel_launch(void* const* d_in, const int* in_sizes, int n_in,
                              void* d_out, int out_size, void* d_ws, size_t ws_size,
                              hipStream_t stream) {
    const float* x    = (const float*)d_in[0];
    const float* W    = (const float*)d_in[1];
    const float* bias = (const float*)d_in[2];
    float* out = (float*)d_out;

    float* ws = (float*)d_ws;
    size_t off = 0;
    float*  sq32 = ws + off;           off += 8192;
    double* sq64 = (double*)(ws + off); off += 16384;
    float*  Wt   = ws + off;           off += 131072;
    float*  wgt  = ws + off;           off += 131072;
    int*    nidx = (int*)(ws + off);   off += 131072;
    float*  xt   = ws + off;           off += 2097152;   // 2M floats
    size_t reuse0 = off;                                  // dead after merge:
    _Float16* xh = (_Float16*)(ws + off); off += 1048576; // 2M halves
    int*    cand = (int*)(ws + off);   off += 163840;     // 8192*20 ints
    size_t vstart = off;
    float*  Vc   = ws + vstart;
    float*  Y1   = ws + reuse0;                           // reuses xh/cand/V
    float*  Y2   = Y1 + 2097152;

    size_t avail = ws_size / 4 > vstart ? ws_size / 4 - vstart : 0;

    sq_kernel<<<32, 256, 0, stream>>>(x, sq32, sq64);
    xt_kernel<<<dim3(64, 4, 2), 256, 0, stream>>>(x, xt, xh);
    wt_kernel<<<dim3(8, 4, 1), 256, 0, stream>>>(W, Wt);

    if (avail >= 33554432u) {
        // mode A: full V for both batches, one select over 8192 queries
        dist_kernel<<<dim3(32, 32, 1), 256, 0, stream>>>(xh, sq32, Vc, 0, 0);
        dist_kernel<<<dim3(32, 32, 1), 256, 0, stream>>>(xh, sq32,
                                                         Vc + (size_t)16777216, 1, 0);
        select2_kernel<<<dim3(2048, 1, 1), 256, 0, stream>>>(Vc, cand, 0);
    } else {
        // mode B: chunked (chunks never cross batch)
        int nch = 2;
        while (nch < 64 && (size_t)(33554432u / nch) > avail) nch <<= 1;
        int cq = 8192 / nch;
        for (int c = 0; c < nch; ++c) {
            int m0 = c * cq;
            int b = m0 >> 12;
            int i0base = m0 & 4095;
            dist_kernel<<<dim3(32, cq / 128, 1), 256, 0, stream>>>(xh, sq32, Vc, b, i0base);
            select2_kernel<<<dim3(cq / 4, 1, 1), 256, 0, stream>>>(Vc, cand, m0);
        }
    }

    merge_rerank<<<128, 256, 0, stream>>>(cand, xt, sq64, nidx, wgt);
    y_kernel<<<dim3(32, 4, 2), 256, 0, stream>>>(x, Wt, bias, Y1, Y2);
    final_kernel<<<8192, 256, 0, stream>>>(Y1, Y2, nidx, wgt, out);
}